// Round 14
// baseline (239.657 us; speedup 1.0000x reference)
//
#include <hip/hip_runtime.h>
#include <hip/hip_bf16.h>
#include <stdint.h>

#define B_ 4
#define S_ 2048
#define H_ 1024
#define NH_ 16
#define HD_ 64
#define SCALE_ 0.125f
#define LOG2E_ 1.4426950408889634f

typedef __bf16 bf16x8 __attribute__((ext_vector_type(8)));
typedef float f32x4 __attribute__((ext_vector_type(4)));
typedef unsigned short us4 __attribute__((ext_vector_type(4)));
typedef unsigned short us8 __attribute__((ext_vector_type(8)));
typedef unsigned short ushort_t;

__device__ __forceinline__ ushort_t f2bf(float f) {
  union { float f; uint32_t u; } a; a.f = f;
  uint32_t r = (a.u + 0x7fffu + ((a.u >> 16) & 1u)) >> 16;
  return (ushort_t)r;
}

__device__ __forceinline__ void async16(const void* g, void* l) {
  __builtin_amdgcn_global_load_lds(
      (const __attribute__((address_space(1))) unsigned int*)(uintptr_t)g,
      (__attribute__((address_space(3))) unsigned int*)(uintptr_t)l, 16, 0, 0);
}

// raw workgroup barrier: no implicit vmcnt/lgkmcnt drain (unlike
// __syncthreads, which drains the global_load_lds queue - m97's ~20% stall).
// "memory" clobber stops the compiler moving LDS/VMEM ops across it.
__device__ __forceinline__ void raw_barrier() {
  asm volatile("s_barrier" ::: "memory");
}

// ------- merged conversion kernel: one launch instead of two ---------
// blocks 0..8191: hidden_states fp32 -> bf16 (conv_x path)
// blocks 8192..8959: W conv+transpose W[k][n] -> Wt[w][n][k] (conv_w)
// Branch is block-uniform -> the barrier in the W path is safe.
__global__ __launch_bounds__(256) void conv_xw(const float4* __restrict__ x,
                                               ushort_t* __restrict__ xb,
                                               const float* __restrict__ Wq,
                                               const float* __restrict__ Wk,
                                               const float* __restrict__ Wv,
                                               ushort_t* __restrict__ Wt) {
  __shared__ __align__(16) ushort_t T[64 * 64];
  int bid = blockIdx.x;
  int tid = threadIdx.x;
  if (bid < 8192) {
    int i = bid * 256 + tid;
    float4 v = x[i];
    us4 o;
    o.x = f2bf(v.x); o.y = f2bf(v.y); o.z = f2bf(v.z); o.w = f2bf(v.w);
    *(us4*)(xb + (size_t)i * 4) = o;
    return;
  }
  int wid = bid - 8192;            // 0..767
  int w = wid >> 8;
  int t2 = wid & 255;
  int kt = (t2 >> 4) * 64, nt = (t2 & 15) * 64;
  const float* W = (w == 0) ? Wq : (w == 1) ? Wk : Wv;
  int k = tid >> 2, nq = tid & 3;
#pragma unroll
  for (int j4 = 0; j4 < 4; ++j4) {
    int n = nq * 4 + j4 * 16;
    float4 f = *(const float4*)(W + (size_t)(kt + k) * H_ + nt + n);
    us4 o;
    o.x = f2bf(f.x); o.y = f2bf(f.y); o.z = f2bf(f.z); o.w = f2bf(f.w);
    *(us4*)(T + k * 64 + (((n >> 3) ^ (k & 7)) * 8) + (n & 7)) = o;
  }
  __syncthreads();
  int n2 = tid >> 2, kq = tid & 3;
  us8 o0, o1;
#pragma unroll
  for (int j = 0; j < 16; ++j) {
    int kk = kq * 16 + j;
    ushort_t v = T[kk * 64 + (((n2 >> 3) ^ (kk & 7)) * 8) + (n2 & 7)];
    if (j < 8) o0[j] = v; else o1[j - 8] = v;
  }
  size_t obase = (size_t)w * (H_ * H_) + (size_t)(nt + n2) * H_ + kt + kq * 16;
  *(us8*)(Wt + obase) = o0;
  *(us8*)(Wt + obase + 8) = o1;
}

// ---------------- fused QKV GEMM (BK=64 + T3 single-barrier dbuf) ----
// Round-14: + nb-grouped XCD swizzle. HW dispatch round-robins blocks
// over 8 XCDs (bid%8). Remap so each XCD owns 3 CONSECUTIVE nb columns
// x all 64 mb: B-panel per XCD = 3x256KB = 768KB, resident in its 4MB
// L2; A rows stream via L3. (R3's failed swizzle chunked mb instead and
// thrashed B.) Bijective: (xcd=flat&7, r=flat>>3) <-> flat; nb=xcd*3+
// (r>>6) covers 0..23; mb=r&63. Compute structure unchanged (BK=64,
// XOR-8 swizzle, raw-barrier dbuf).
// w==2 (V) epilogue writes transposed [bh][d][s] into the V slot so attn
// can stage V^T directly.
__global__ __launch_bounds__(256) void qkv_gemm(const ushort_t* __restrict__ Xb,
                                                const ushort_t* __restrict__ Wt,
                                                const float* __restrict__ bq,
                                                const float* __restrict__ bk,
                                                const float* __restrict__ bv,
                                                ushort_t* __restrict__ QKV) {
  __shared__ __align__(16) ushort_t As0[128 * 64];   // 16 KB
  __shared__ __align__(16) ushort_t As1[128 * 64];   // 16 KB
  __shared__ __align__(16) ushort_t Bs0[128 * 64];   // 16 KB
  __shared__ __align__(16) ushort_t Bs1[128 * 64];   // 16 KB
  int flat = blockIdx.y * 24 + blockIdx.x;
  int xcd = flat & 7, r = flat >> 3;
  int nb = xcd * 3 + (r >> 6);     // 3 consecutive nb columns per XCD
  int mb = r & 63;
  int w = nb >> 3;
  int n_base = (nb & 7) * 128;
  int m_base = mb * 128;
  const ushort_t* Wtw = Wt + (size_t)w * (H_ * H_);
  int tid = threadIdx.x;
  int lane = tid & 63, wave = tid >> 6;
  int wr = wave >> 1, wc = wave & 1;
  int g = lane >> 4, l15 = lane & 15;

  f32x4 acc[4][4];
#pragma unroll
  for (int i = 0; i < 4; i++)
#pragma unroll
    for (int j = 0; j < 4; j++) acc[i][j] = (f32x4){0.f, 0.f, 0.f, 0.f};

  // staging: 8 chunks/thread/iter (4 for A, 4 for B). chunk id = tid+it*256
  // -> (row = id>>3, slot = id&7); rows step by 32 per it (low 3 bits of
  // row invariant -> one source-column xor per thread).
  int r0 = tid >> 3, sl = tid & 7;
  int cc = sl ^ (r0 & 7);
  const ushort_t* sA = Xb + (size_t)(m_base + r0) * H_ + cc * 8;
  const ushort_t* sB = Wtw + (size_t)(n_base + r0) * H_ + cc * 8;
  int la = tid * 8;                // ushort offset of chunk id (it adds 2048)

  // prologue: stage tile 0, publish
#pragma unroll
  for (int it = 0; it < 4; ++it) {
    async16(sA + (size_t)it * 32 * H_, As0 + la + it * 2048);
    async16(sB + (size_t)it * 32 * H_, Bs0 + la + it * 2048);
  }
  __builtin_amdgcn_s_waitcnt(0xF70);   // vmcnt(0)
  raw_barrier();

  for (int kt = 0; kt < 16; ++kt) {
    const ushort_t* Ac = (kt & 1) ? As1 : As0;
    const ushort_t* Bc = (kt & 1) ? Bs1 : Bs0;
    ushort_t* An = (kt & 1) ? As0 : As1;
    ushort_t* Bn = (kt & 1) ? Bs0 : Bs1;
    if (kt < 15) {
      int k0 = (kt + 1) * 64;
#pragma unroll
      for (int it = 0; it < 4; ++it) {
        async16(sA + (size_t)it * 32 * H_ + k0, An + la + it * 2048);
        async16(sB + (size_t)it * 32 * H_ + k0, Bn + la + it * 2048);
      }
    }

#pragma unroll
    for (int ks = 0; ks < 2; ++ks) {
      bf16x8 af[4], bfr[4];
#pragma unroll
      for (int mi = 0; mi < 4; mi++) {
        int row = wr * 64 + mi * 16 + l15;
        af[mi] = *(const bf16x8*)(Ac + row * 64 + (((ks * 4 + g) ^ (row & 7)) * 8));
      }
#pragma unroll
      for (int ni = 0; ni < 4; ni++) {
        int row = wc * 64 + ni * 16 + l15;
        bfr[ni] = *(const bf16x8*)(Bc + row * 64 + (((ks * 4 + g) ^ (row & 7)) * 8));
      }
#pragma unroll
      for (int mi = 0; mi < 4; mi++)
#pragma unroll
        for (int ni = 0; ni < 4; ni++)
          acc[mi][ni] = __builtin_amdgcn_mfma_f32_16x16x32_bf16(af[mi], bfr[ni], acc[mi][ni], 0, 0, 0);
    }

    if (kt < 15) {
      __builtin_amdgcn_s_waitcnt(0xF70);   // vmcnt(0): tile kt+1 landed
      raw_barrier();                       // publish; no re-drain
    }
  }

  const float* bias = (w == 0) ? bq : (w == 1) ? bk : bv;
  float mult = (w == 0) ? SCALE_ * LOG2E_ : 1.0f;  // fold scale*log2e into Q
  if (w == 2) {
    // V: write transposed Vt[bh][d][s], 8B stores (4 consecutive s per lane)
    ushort_t* Vout = QKV + 16777216u;
#pragma unroll
    for (int ni = 0; ni < 4; ++ni) {
      int n_col = n_base + wc * 64 + ni * 16 + l15;
      float bb = bias[n_col];
      int hh = n_col >> 6, d = n_col & 63;
#pragma unroll
      for (int mi = 0; mi < 4; ++mi) {
        int m_row = m_base + wr * 64 + mi * 16 + g * 4;
        int bbi = m_row >> 11, s = m_row & 2047;
        us4 o;
#pragma unroll
        for (int reg = 0; reg < 4; ++reg) o[reg] = f2bf(acc[mi][ni][reg] + bb);
        *(us4*)(Vout + ((size_t)((bbi * 16 + hh) * 64 + d)) * 2048 + s) = o;
      }
    }
  } else {
    ushort_t* out = QKV + (size_t)w * (8192u * 1024u);
#pragma unroll
    for (int ni = 0; ni < 4; ++ni) {
      int n_col = n_base + wc * 64 + ni * 16 + l15;
      float bb = bias[n_col];
#pragma unroll
      for (int mi = 0; mi < 4; ++mi) {
        int m_row = m_base + wr * 64 + mi * 16 + g * 4;
#pragma unroll
        for (int reg = 0; reg < 4; ++reg) {
          float v = (acc[mi][ni][reg] + bb) * mult;
          out[(size_t)(m_row + reg) * H_ + n_col] = f2bf(v);
        }
      }
    }
  }
}

// ---------------- flash attention, zero-P-LDS form -------------------
// Round-14: round-13's structure (triple-buffer single-barrier, trunc
// pack, 69.9 us) with the inner loop re-pipelined: (1) all setprio
// removed (measured-null in R10; side-effecting -> pins the schedule),
// (2) per kk, BOTH mi's S-MFMAs issue as one 8-MFMA burst before any
// softmax, so exp2(mi=0) overlaps the burst tail on the matrix pipe and
// PV(mi=0) overlaps exp2(mi=1). Per-accumulator operation order is
// unchanged -> bit-identical output. VGPR ~68 (<=128, 4 waves/SIMD).
__global__ __launch_bounds__(512, 4) void attn(const ushort_t* __restrict__ QKV,
                                               const ushort_t* __restrict__ Vt,
                                               float* __restrict__ out) {
  __shared__ __align__(16) ushort_t Ks[3][64 * 64];   // 24 KB
  __shared__ __align__(16) ushort_t Vs[3][64 * 64];   // 24 KB
  int qt = blockIdx.x;   // 0..7
  int bh = blockIdx.y;   // 0..63
  int b = bh >> 4, h = bh & 15;
  int tid = threadIdx.x, lane = tid & 63, wave = tid >> 6;  // wave 0..7
  int g = lane >> 4, l15 = lane & 15;

  const ushort_t* Qb = QKV;
  const ushort_t* Kb = QKV + 8388608u;

  // Q B-frags: 32 q rows per wave (scale*log2e pre-folded into Q)
  bf16x8 qf[2][2];
#pragma unroll
  for (int mi = 0; mi < 2; ++mi) {
    int q_row = qt * 256 + wave * 32 + mi * 16 + l15;
    size_t qoff = (size_t)(b * S_ + q_row) * H_ + h * HD_;
    qf[mi][0] = *(const bf16x8*)(Qb + qoff + g * 8);
    qf[mi][1] = *(const bf16x8*)(Qb + qoff + 32 + g * 8);
  }

  // all-ones A-fragment for the row-sum MFMA (bit pattern 0x3F80 = bf16 1.0)
  union { us8 u; bf16x8 v; } ones_u;
#pragma unroll
  for (int i = 0; i < 8; ++i) ones_u.u[i] = 0x3F80;
  bf16x8 onesf = ones_u.v;

  f32x4 of[2][4];
  f32x4 lacc[2];
#pragma unroll
  for (int mi = 0; mi < 2; mi++) {
    lacc[mi] = (f32x4){0.f, 0.f, 0.f, 0.f};
#pragma unroll
    for (int ni = 0; ni < 4; ni++) of[mi][ni] = (f32x4){0.f, 0.f, 0.f, 0.f};
  }

  // interleaved A-row for S^T: row_a = kk*32 + (l15>>2)*8 + (l15&3), row_b = +4
  int ra = (l15 >> 2) * 8 + (l15 & 3);
  int sKa = ((l15 >> 2) & 1) * 4 + (l15 & 3);   // sigma_K of both rows
  int posK0 = (g ^ sKa) * 8, posK1 = ((4 + g) ^ sKa) * 8;

  // staging: 512 threads x 1 chunk per 8KB tile (K and V each)
  int ch = tid;                    // 0..511
  int s0 = ch >> 3;
  int cK = (ch & 7) ^ ((((s0 >> 3) & 1) << 2) | (s0 & 3));
  int cV = (ch & 7) ^ (s0 & 7);
  const ushort_t* srcK = Kb + (size_t)(b * S_ + s0) * H_ + h * HD_ + cK * 8;
  const ushort_t* srcV = Vt + ((size_t)bh * 64 + s0) * S_ + cV * 8;

  // preload tile 0 into buffer 0
  async16(srcK, Ks[0] + ch * 8);
  async16(srcV, Vs[0] + ch * 8);

  // rotation: Kc/Vc = current tile t; Kw/Vw = write target (holds t-2);
  // Kp/Vp = previous (t-1, may still be under read by laggard waves).
  const ushort_t* Kc = Ks[0];
  const ushort_t* Vc = Vs[0];
  ushort_t* Kw = (ushort_t*)Ks[1];
  ushort_t* Vw = (ushort_t*)Vs[1];
  const ushort_t* Kp = Ks[2];
  const ushort_t* Vp = Vs[2];

  for (int kb = 0; kb < 32; ++kb) {
    if (kb < 31) {
      async16(srcK + (size_t)(kb + 1) * 64 * H_, Kw + ch * 8);
      async16(srcV + (size_t)(kb + 1) * 64, Vw + ch * 8);
      __builtin_amdgcn_s_waitcnt(0xF72);   // vmcnt(2): own tile-kb loads landed
    } else {
      __builtin_amdgcn_s_waitcnt(0xF70);   // vmcnt(0)
    }
    raw_barrier();                          // publish tile kb (single barrier)

#pragma unroll
    for (int kk = 0; kk < 2; ++kk) {
      int rowa = kk * 32 + ra;
      int rowb = rowa + 4;
      bf16x8 ka0 = *(const bf16x8*)(Kc + rowa * 64 + posK0);
      bf16x8 ka1 = *(const bf16x8*)(Kc + rowa * 64 + posK1);
      bf16x8 kb0 = *(const bf16x8*)(Kc + rowb * 64 + posK0);
      bf16x8 kb1 = *(const bf16x8*)(Kc + rowb * 64 + posK1);
      bf16x8 vf[4];
#pragma unroll
      for (int ni = 0; ni < 4; ++ni) {
        int row = ni * 16 + l15;
        vf[ni] = *(const bf16x8*)(Vc + row * 64 + (((kk * 4 + g) ^ (row & 7)) * 8));
      }
      // S-burst: both mi's QK^T MFMAs issued back-to-back (8 MFMAs) so
      // the softmax VALU work below overlaps the matrix pipe's tail.
      f32x4 s00 = (f32x4){0.f, 0.f, 0.f, 0.f};
      f32x4 s01 = (f32x4){0.f, 0.f, 0.f, 0.f};
      f32x4 s10 = (f32x4){0.f, 0.f, 0.f, 0.f};
      f32x4 s11 = (f32x4){0.f, 0.f, 0.f, 0.f};
      s00 = __builtin_amdgcn_mfma_f32_16x16x32_bf16(ka0, qf[0][0], s00, 0, 0, 0);
      s00 = __builtin_amdgcn_mfma_f32_16x16x32_bf16(ka1, qf[0][1], s00, 0, 0, 0);
      s01 = __builtin_amdgcn_mfma_f32_16x16x32_bf16(kb0, qf[0][0], s01, 0, 0, 0);
      s01 = __builtin_amdgcn_mfma_f32_16x16x32_bf16(kb1, qf[0][1], s01, 0, 0, 0);
      s10 = __builtin_amdgcn_mfma_f32_16x16x32_bf16(ka0, qf[1][0], s10, 0, 0, 0);
      s10 = __builtin_amdgcn_mfma_f32_16x16x32_bf16(ka1, qf[1][1], s10, 0, 0, 0);
      s11 = __builtin_amdgcn_mfma_f32_16x16x32_bf16(kb0, qf[1][0], s11, 0, 0, 0);
      s11 = __builtin_amdgcn_mfma_f32_16x16x32_bf16(kb1, qf[1][1], s11, 0, 0, 0);
#pragma unroll
      for (int mi = 0; mi < 2; ++mi) {
        f32x4 sa = (mi == 0) ? s00 : s10;
        f32x4 sb = (mi == 0) ? s01 : s11;
        float pa0 = __builtin_amdgcn_exp2f(sa[0]);
        float pa1 = __builtin_amdgcn_exp2f(sa[1]);
        float pa2 = __builtin_amdgcn_exp2f(sa[2]);
        float pa3 = __builtin_amdgcn_exp2f(sa[3]);
        float pb0 = __builtin_amdgcn_exp2f(sb[0]);
        float pb1 = __builtin_amdgcn_exp2f(sb[1]);
        float pb2 = __builtin_amdgcn_exp2f(sb[2]);
        float pb3 = __builtin_amdgcn_exp2f(sb[3]);
        union { bf16x8 v; unsigned int u[4]; } pf;
        // truncation pack: high-16 extraction only (no +0x8000 RNE adds).
        // Denominator (lacc) uses the same truncated pf -> bias cancels.
        pf.u[0] = __builtin_amdgcn_perm(__float_as_uint(pa1),
                                        __float_as_uint(pa0), 0x07060302u);
        pf.u[1] = __builtin_amdgcn_perm(__float_as_uint(pa3),
                                        __float_as_uint(pa2), 0x07060302u);
        pf.u[2] = __builtin_amdgcn_perm(__float_as_uint(pb1),
                                        __float_as_uint(pb0), 0x07060302u);
        pf.u[3] = __builtin_amdgcn_perm(__float_as_uint(pb3),
                                        __float_as_uint(pb2), 0x07060302u);
#pragma unroll
        for (int ni = 0; ni < 4; ++ni)
          of[mi][ni] = __builtin_amdgcn_mfma_f32_16x16x32_bf16(vf[ni], pf.v, of[mi][ni], 0, 0, 0);
        // row-sum on the matrix pipe: lacc[mi][*] = sum_k P[k][q=l15]
        lacc[mi] = __builtin_amdgcn_mfma_f32_16x16x32_bf16(onesf, pf.v, lacc[mi], 0, 0, 0);
      }
    }

    // rotate buffers: (Kp, Kc, Kw) <- (Kc, Kw, Kp)
    const ushort_t* tK = Kp; Kp = Kc; Kc = Kw; Kw = (ushort_t*)tK;
    const ushort_t* tV = Vp; Vp = Vc; Vc = Vw; Vw = (ushort_t*)tV;
  }

  // ---- epilogue: O^T / l, float4 stores (no shfl: lacc holds full sum) ----
#pragma unroll
  for (int mi = 0; mi < 2; ++mi) {
    float inv = 1.0f / lacc[mi][0];
    int qglob = qt * 256 + wave * 32 + mi * 16 + l15;
    float* obase = out + (size_t)(b * S_ + qglob) * H_ + h * HD_ + g * 4;
#pragma unroll
    for (int ni = 0; ni < 4; ++ni) {
      float4 vv;
      vv.x = of[mi][ni][0] * inv;
      vv.y = of[mi][ni][1] * inv;
      vv.z = of[mi][ni][2] * inv;
      vv.w = of[mi][ni][3] * inv;
      *(float4*)(obase + ni * 16) = vv;
    }
  }
}

extern "C" void kernel_launch(void* const* d_in, const int* in_sizes, int n_in,
                              void* d_out, int out_size, void* d_ws, size_t ws_size,
                              hipStream_t stream) {
  const float* hs = (const float*)d_in[0];
  const float* Wq = (const float*)d_in[1];
  const float* bq = (const float*)d_in[2];
  const float* Wk = (const float*)d_in[3];
  const float* bk = (const float*)d_in[4];
  const float* Wv = (const float*)d_in[5];
  const float* bv = (const float*)d_in[6];
  float* out = (float*)d_out;

  // ws (bf16): Xb[8M] | Wt[3M] | QKV[24M]; V slot holds Vt[bh][d][s].
  ushort_t* Xb  = (ushort_t*)d_ws;
  ushort_t* Wt  = Xb + 8388608u;
  ushort_t* QKV = Wt + 3145728u;
  ushort_t* Vtp = QKV + 16777216u;

  conv_xw<<<8960, 256, 0, stream>>>((const float4*)hs, Xb, Wq, Wk, Wv, Wt);
  qkv_gemm<<<dim3(24, 64), 256, 0, stream>>>(Xb, Wt, bq, bk, bv, QKV);
  attn<<<dim3(8, 64), 512, 0, stream>>>(QKV, Vtp, out);
}

// Round 15
// 230.843 us; speedup vs baseline: 1.0382x; 1.0382x over previous
//
#include <hip/hip_runtime.h>
#include <hip/hip_bf16.h>
#include <stdint.h>

#define B_ 4
#define S_ 2048
#define H_ 1024
#define NH_ 16
#define HD_ 64
#define SCALE_ 0.125f
#define LOG2E_ 1.4426950408889634f

typedef __bf16 bf16x8 __attribute__((ext_vector_type(8)));
typedef float f32x4 __attribute__((ext_vector_type(4)));
typedef unsigned short us4 __attribute__((ext_vector_type(4)));
typedef unsigned short us8 __attribute__((ext_vector_type(8)));
typedef unsigned short ushort_t;

__device__ __forceinline__ ushort_t f2bf(float f) {
  union { float f; uint32_t u; } a; a.f = f;
  uint32_t r = (a.u + 0x7fffu + ((a.u >> 16) & 1u)) >> 16;
  return (ushort_t)r;
}

__device__ __forceinline__ void async16(const void* g, void* l) {
  __builtin_amdgcn_global_load_lds(
      (const __attribute__((address_space(1))) unsigned int*)(uintptr_t)g,
      (__attribute__((address_space(3))) unsigned int*)(uintptr_t)l, 16, 0, 0);
}

// raw workgroup barrier: no implicit vmcnt/lgkmcnt drain (unlike
// __syncthreads, which drains the global_load_lds queue - m97's ~20% stall).
// "memory" clobber stops the compiler moving LDS/VMEM ops across it.
__device__ __forceinline__ void raw_barrier() {
  asm volatile("s_barrier" ::: "memory");
}

// ------- merged conversion kernel: one launch instead of two ---------
// blocks 0..8191: hidden_states fp32 -> bf16 (conv_x path)
// blocks 8192..8959: W conv+transpose W[k][n] -> Wt[w][n][k] (conv_w)
// Branch is block-uniform -> the barrier in the W path is safe.
__global__ __launch_bounds__(256) void conv_xw(const float4* __restrict__ x,
                                               ushort_t* __restrict__ xb,
                                               const float* __restrict__ Wq,
                                               const float* __restrict__ Wk,
                                               const float* __restrict__ Wv,
                                               ushort_t* __restrict__ Wt) {
  __shared__ __align__(16) ushort_t T[64 * 64];
  int bid = blockIdx.x;
  int tid = threadIdx.x;
  if (bid < 8192) {
    int i = bid * 256 + tid;
    float4 v = x[i];
    us4 o;
    o.x = f2bf(v.x); o.y = f2bf(v.y); o.z = f2bf(v.z); o.w = f2bf(v.w);
    *(us4*)(xb + (size_t)i * 4) = o;
    return;
  }
  int wid = bid - 8192;            // 0..767
  int w = wid >> 8;
  int t2 = wid & 255;
  int kt = (t2 >> 4) * 64, nt = (t2 & 15) * 64;
  const float* W = (w == 0) ? Wq : (w == 1) ? Wk : Wv;
  int k = tid >> 2, nq = tid & 3;
#pragma unroll
  for (int j4 = 0; j4 < 4; ++j4) {
    int n = nq * 4 + j4 * 16;
    float4 f = *(const float4*)(W + (size_t)(kt + k) * H_ + nt + n);
    us4 o;
    o.x = f2bf(f.x); o.y = f2bf(f.y); o.z = f2bf(f.z); o.w = f2bf(f.w);
    *(us4*)(T + k * 64 + (((n >> 3) ^ (k & 7)) * 8) + (n & 7)) = o;
  }
  __syncthreads();
  int n2 = tid >> 2, kq = tid & 3;
  us8 o0, o1;
#pragma unroll
  for (int j = 0; j < 16; ++j) {
    int kk = kq * 16 + j;
    ushort_t v = T[kk * 64 + (((n2 >> 3) ^ (kk & 7)) * 8) + (n2 & 7)];
    if (j < 8) o0[j] = v; else o1[j - 8] = v;
  }
  size_t obase = (size_t)w * (H_ * H_) + (size_t)(nt + n2) * H_ + kt + kq * 16;
  *(us8*)(Wt + obase) = o0;
  *(us8*)(Wt + obase + 8) = o1;
}

// ---------------- fused QKV GEMM (BK=64 + T3 single-barrier dbuf) ----
// Round-15: XCD swizzle REVERTED (R14's nb-grouping made each XCD
// stream all of A: FETCH 77->200MB, dur +10us. R3's mb-chunk also
// regressed. Lesson: default round-robin dispatch + L3 panel sharing
// beats per-XCD ownership on these small matrices - no more swizzles.)
// Structure = round-13 form: BK=64, XOR-8 swizzle, raw-barrier dbuf.
// w==2 (V) epilogue writes transposed [bh][d][s] into the V slot so attn
// can stage V^T directly.
__global__ __launch_bounds__(256) void qkv_gemm(const ushort_t* __restrict__ Xb,
                                                const ushort_t* __restrict__ Wt,
                                                const float* __restrict__ bq,
                                                const float* __restrict__ bk,
                                                const float* __restrict__ bv,
                                                ushort_t* __restrict__ QKV) {
  __shared__ __align__(16) ushort_t As0[128 * 64];   // 16 KB
  __shared__ __align__(16) ushort_t As1[128 * 64];   // 16 KB
  __shared__ __align__(16) ushort_t Bs0[128 * 64];   // 16 KB
  __shared__ __align__(16) ushort_t Bs1[128 * 64];   // 16 KB
  int nb = blockIdx.x;             // 0..23
  int mb = blockIdx.y;             // 0..63
  int w = nb >> 3;
  int n_base = (nb & 7) * 128;
  int m_base = mb * 128;
  const ushort_t* Wtw = Wt + (size_t)w * (H_ * H_);
  int tid = threadIdx.x;
  int lane = tid & 63, wave = tid >> 6;
  int wr = wave >> 1, wc = wave & 1;
  int g = lane >> 4, l15 = lane & 15;

  f32x4 acc[4][4];
#pragma unroll
  for (int i = 0; i < 4; i++)
#pragma unroll
    for (int j = 0; j < 4; j++) acc[i][j] = (f32x4){0.f, 0.f, 0.f, 0.f};

  // staging: 8 chunks/thread/iter (4 for A, 4 for B). chunk id = tid+it*256
  // -> (row = id>>3, slot = id&7); rows step by 32 per it (low 3 bits of
  // row invariant -> one source-column xor per thread).
  int r0 = tid >> 3, sl = tid & 7;
  int cc = sl ^ (r0 & 7);
  const ushort_t* sA = Xb + (size_t)(m_base + r0) * H_ + cc * 8;
  const ushort_t* sB = Wtw + (size_t)(n_base + r0) * H_ + cc * 8;
  int la = tid * 8;                // ushort offset of chunk id (it adds 2048)

  // prologue: stage tile 0, publish
#pragma unroll
  for (int it = 0; it < 4; ++it) {
    async16(sA + (size_t)it * 32 * H_, As0 + la + it * 2048);
    async16(sB + (size_t)it * 32 * H_, Bs0 + la + it * 2048);
  }
  __builtin_amdgcn_s_waitcnt(0xF70);   // vmcnt(0)
  raw_barrier();

  for (int kt = 0; kt < 16; ++kt) {
    const ushort_t* Ac = (kt & 1) ? As1 : As0;
    const ushort_t* Bc = (kt & 1) ? Bs1 : Bs0;
    ushort_t* An = (kt & 1) ? As0 : As1;
    ushort_t* Bn = (kt & 1) ? Bs0 : Bs1;
    if (kt < 15) {
      int k0 = (kt + 1) * 64;
#pragma unroll
      for (int it = 0; it < 4; ++it) {
        async16(sA + (size_t)it * 32 * H_ + k0, An + la + it * 2048);
        async16(sB + (size_t)it * 32 * H_ + k0, Bn + la + it * 2048);
      }
    }

#pragma unroll
    for (int ks = 0; ks < 2; ++ks) {
      bf16x8 af[4], bfr[4];
#pragma unroll
      for (int mi = 0; mi < 4; mi++) {
        int row = wr * 64 + mi * 16 + l15;
        af[mi] = *(const bf16x8*)(Ac + row * 64 + (((ks * 4 + g) ^ (row & 7)) * 8));
      }
#pragma unroll
      for (int ni = 0; ni < 4; ni++) {
        int row = wc * 64 + ni * 16 + l15;
        bfr[ni] = *(const bf16x8*)(Bc + row * 64 + (((ks * 4 + g) ^ (row & 7)) * 8));
      }
#pragma unroll
      for (int mi = 0; mi < 4; mi++)
#pragma unroll
        for (int ni = 0; ni < 4; ni++)
          acc[mi][ni] = __builtin_amdgcn_mfma_f32_16x16x32_bf16(af[mi], bfr[ni], acc[mi][ni], 0, 0, 0);
    }

    if (kt < 15) {
      __builtin_amdgcn_s_waitcnt(0xF70);   // vmcnt(0): tile kt+1 landed
      raw_barrier();                       // publish; no re-drain
    }
  }

  const float* bias = (w == 0) ? bq : (w == 1) ? bk : bv;
  float mult = (w == 0) ? SCALE_ * LOG2E_ : 1.0f;  // fold scale*log2e into Q
  if (w == 2) {
    // V: write transposed Vt[bh][d][s], 8B stores (4 consecutive s per lane)
    ushort_t* Vout = QKV + 16777216u;
#pragma unroll
    for (int ni = 0; ni < 4; ++ni) {
      int n_col = n_base + wc * 64 + ni * 16 + l15;
      float bb = bias[n_col];
      int hh = n_col >> 6, d = n_col & 63;
#pragma unroll
      for (int mi = 0; mi < 4; ++mi) {
        int m_row = m_base + wr * 64 + mi * 16 + g * 4;
        int bbi = m_row >> 11, s = m_row & 2047;
        us4 o;
#pragma unroll
        for (int reg = 0; reg < 4; ++reg) o[reg] = f2bf(acc[mi][ni][reg] + bb);
        *(us4*)(Vout + ((size_t)((bbi * 16 + hh) * 64 + d)) * 2048 + s) = o;
      }
    }
  } else {
    ushort_t* out = QKV + (size_t)w * (8192u * 1024u);
#pragma unroll
    for (int ni = 0; ni < 4; ++ni) {
      int n_col = n_base + wc * 64 + ni * 16 + l15;
      float bb = bias[n_col];
#pragma unroll
      for (int mi = 0; mi < 4; ++mi) {
        int m_row = m_base + wr * 64 + mi * 16 + g * 4;
#pragma unroll
        for (int reg = 0; reg < 4; ++reg) {
          float v = (acc[mi][ni][reg] + bb) * mult;
          out[(size_t)(m_row + reg) * H_ + n_col] = f2bf(v);
        }
      }
    }
  }
}

// ---------------- flash attention, zero-P-LDS form -------------------
// Round-15: attn unchanged from R14 (triple-buffer single-barrier,
// trunc pack, S-burst: both mi's QK^T as one 8-MFMA burst, no setprio).
// R14's qkv regression hid attn below the top-5; this round's qkv
// revert makes R15-attn vs R13's 69.9us the clean S-burst readout.
__global__ __launch_bounds__(512, 4) void attn(const ushort_t* __restrict__ QKV,
                                               const ushort_t* __restrict__ Vt,
                                               float* __restrict__ out) {
  __shared__ __align__(16) ushort_t Ks[3][64 * 64];   // 24 KB
  __shared__ __align__(16) ushort_t Vs[3][64 * 64];   // 24 KB
  int qt = blockIdx.x;   // 0..7
  int bh = blockIdx.y;   // 0..63
  int b = bh >> 4, h = bh & 15;
  int tid = threadIdx.x, lane = tid & 63, wave = tid >> 6;  // wave 0..7
  int g = lane >> 4, l15 = lane & 15;

  const ushort_t* Qb = QKV;
  const ushort_t* Kb = QKV + 8388608u;

  // Q B-frags: 32 q rows per wave (scale*log2e pre-folded into Q)
  bf16x8 qf[2][2];
#pragma unroll
  for (int mi = 0; mi < 2; ++mi) {
    int q_row = qt * 256 + wave * 32 + mi * 16 + l15;
    size_t qoff = (size_t)(b * S_ + q_row) * H_ + h * HD_;
    qf[mi][0] = *(const bf16x8*)(Qb + qoff + g * 8);
    qf[mi][1] = *(const bf16x8*)(Qb + qoff + 32 + g * 8);
  }

  // all-ones A-fragment for the row-sum MFMA (bit pattern 0x3F80 = bf16 1.0)
  union { us8 u; bf16x8 v; } ones_u;
#pragma unroll
  for (int i = 0; i < 8; ++i) ones_u.u[i] = 0x3F80;
  bf16x8 onesf = ones_u.v;

  f32x4 of[2][4];
  f32x4 lacc[2];
#pragma unroll
  for (int mi = 0; mi < 2; mi++) {
    lacc[mi] = (f32x4){0.f, 0.f, 0.f, 0.f};
#pragma unroll
    for (int ni = 0; ni < 4; ni++) of[mi][ni] = (f32x4){0.f, 0.f, 0.f, 0.f};
  }

  // interleaved A-row for S^T: row_a = kk*32 + (l15>>2)*8 + (l15&3), row_b = +4
  int ra = (l15 >> 2) * 8 + (l15 & 3);
  int sKa = ((l15 >> 2) & 1) * 4 + (l15 & 3);   // sigma_K of both rows
  int posK0 = (g ^ sKa) * 8, posK1 = ((4 + g) ^ sKa) * 8;

  // staging: 512 threads x 1 chunk per 8KB tile (K and V each)
  int ch = tid;                    // 0..511
  int s0 = ch >> 3;
  int cK = (ch & 7) ^ ((((s0 >> 3) & 1) << 2) | (s0 & 3));
  int cV = (ch & 7) ^ (s0 & 7);
  const ushort_t* srcK = Kb + (size_t)(b * S_ + s0) * H_ + h * HD_ + cK * 8;
  const ushort_t* srcV = Vt + ((size_t)bh * 64 + s0) * S_ + cV * 8;

  // preload tile 0 into buffer 0
  async16(srcK, Ks[0] + ch * 8);
  async16(srcV, Vs[0] + ch * 8);

  // rotation: Kc/Vc = current tile t; Kw/Vw = write target (holds t-2);
  // Kp/Vp = previous (t-1, may still be under read by laggard waves).
  const ushort_t* Kc = Ks[0];
  const ushort_t* Vc = Vs[0];
  ushort_t* Kw = (ushort_t*)Ks[1];
  ushort_t* Vw = (ushort_t*)Vs[1];
  const ushort_t* Kp = Ks[2];
  const ushort_t* Vp = Vs[2];

  for (int kb = 0; kb < 32; ++kb) {
    if (kb < 31) {
      async16(srcK + (size_t)(kb + 1) * 64 * H_, Kw + ch * 8);
      async16(srcV + (size_t)(kb + 1) * 64, Vw + ch * 8);
      __builtin_amdgcn_s_waitcnt(0xF72);   // vmcnt(2): own tile-kb loads landed
    } else {
      __builtin_amdgcn_s_waitcnt(0xF70);   // vmcnt(0)
    }
    raw_barrier();                          // publish tile kb (single barrier)

#pragma unroll
    for (int kk = 0; kk < 2; ++kk) {
      int rowa = kk * 32 + ra;
      int rowb = rowa + 4;
      bf16x8 ka0 = *(const bf16x8*)(Kc + rowa * 64 + posK0);
      bf16x8 ka1 = *(const bf16x8*)(Kc + rowa * 64 + posK1);
      bf16x8 kb0 = *(const bf16x8*)(Kc + rowb * 64 + posK0);
      bf16x8 kb1 = *(const bf16x8*)(Kc + rowb * 64 + posK1);
      bf16x8 vf[4];
#pragma unroll
      for (int ni = 0; ni < 4; ++ni) {
        int row = ni * 16 + l15;
        vf[ni] = *(const bf16x8*)(Vc + row * 64 + (((kk * 4 + g) ^ (row & 7)) * 8));
      }
      // S-burst: both mi's QK^T MFMAs issued back-to-back (8 MFMAs) so
      // the softmax VALU work below overlaps the matrix pipe's tail.
      f32x4 s00 = (f32x4){0.f, 0.f, 0.f, 0.f};
      f32x4 s01 = (f32x4){0.f, 0.f, 0.f, 0.f};
      f32x4 s10 = (f32x4){0.f, 0.f, 0.f, 0.f};
      f32x4 s11 = (f32x4){0.f, 0.f, 0.f, 0.f};
      s00 = __builtin_amdgcn_mfma_f32_16x16x32_bf16(ka0, qf[0][0], s00, 0, 0, 0);
      s00 = __builtin_amdgcn_mfma_f32_16x16x32_bf16(ka1, qf[0][1], s00, 0, 0, 0);
      s01 = __builtin_amdgcn_mfma_f32_16x16x32_bf16(kb0, qf[0][0], s01, 0, 0, 0);
      s01 = __builtin_amdgcn_mfma_f32_16x16x32_bf16(kb1, qf[0][1], s01, 0, 0, 0);
      s10 = __builtin_amdgcn_mfma_f32_16x16x32_bf16(ka0, qf[1][0], s10, 0, 0, 0);
      s10 = __builtin_amdgcn_mfma_f32_16x16x32_bf16(ka1, qf[1][1], s10, 0, 0, 0);
      s11 = __builtin_amdgcn_mfma_f32_16x16x32_bf16(kb0, qf[1][0], s11, 0, 0, 0);
      s11 = __builtin_amdgcn_mfma_f32_16x16x32_bf16(kb1, qf[1][1], s11, 0, 0, 0);
#pragma unroll
      for (int mi = 0; mi < 2; ++mi) {
        f32x4 sa = (mi == 0) ? s00 : s10;
        f32x4 sb = (mi == 0) ? s01 : s11;
        float pa0 = __builtin_amdgcn_exp2f(sa[0]);
        float pa1 = __builtin_amdgcn_exp2f(sa[1]);
        float pa2 = __builtin_amdgcn_exp2f(sa[2]);
        float pa3 = __builtin_amdgcn_exp2f(sa[3]);
        float pb0 = __builtin_amdgcn_exp2f(sb[0]);
        float pb1 = __builtin_amdgcn_exp2f(sb[1]);
        float pb2 = __builtin_amdgcn_exp2f(sb[2]);
        float pb3 = __builtin_amdgcn_exp2f(sb[3]);
        union { bf16x8 v; unsigned int u[4]; } pf;
        // truncation pack: high-16 extraction only (no +0x8000 RNE adds).
        // Denominator (lacc) uses the same truncated pf -> bias cancels.
        pf.u[0] = __builtin_amdgcn_perm(__float_as_uint(pa1),
                                        __float_as_uint(pa0), 0x07060302u);
        pf.u[1] = __builtin_amdgcn_perm(__float_as_uint(pa3),
                                        __float_as_uint(pa2), 0x07060302u);
        pf.u[2] = __builtin_amdgcn_perm(__float_as_uint(pb1),
                                        __float_as_uint(pb0), 0x07060302u);
        pf.u[3] = __builtin_amdgcn_perm(__float_as_uint(pb3),
                                        __float_as_uint(pb2), 0x07060302u);
#pragma unroll
        for (int ni = 0; ni < 4; ++ni)
          of[mi][ni] = __builtin_amdgcn_mfma_f32_16x16x32_bf16(vf[ni], pf.v, of[mi][ni], 0, 0, 0);
        // row-sum on the matrix pipe: lacc[mi][*] = sum_k P[k][q=l15]
        lacc[mi] = __builtin_amdgcn_mfma_f32_16x16x32_bf16(onesf, pf.v, lacc[mi], 0, 0, 0);
      }
    }

    // rotate buffers: (Kp, Kc, Kw) <- (Kc, Kw, Kp)
    const ushort_t* tK = Kp; Kp = Kc; Kc = Kw; Kw = (ushort_t*)tK;
    const ushort_t* tV = Vp; Vp = Vc; Vc = Vw; Vw = (ushort_t*)tV;
  }

  // ---- epilogue: O^T / l, float4 stores (no shfl: lacc holds full sum) ----
#pragma unroll
  for (int mi = 0; mi < 2; ++mi) {
    float inv = 1.0f / lacc[mi][0];
    int qglob = qt * 256 + wave * 32 + mi * 16 + l15;
    float* obase = out + (size_t)(b * S_ + qglob) * H_ + h * HD_ + g * 4;
#pragma unroll
    for (int ni = 0; ni < 4; ++ni) {
      float4 vv;
      vv.x = of[mi][ni][0] * inv;
      vv.y = of[mi][ni][1] * inv;
      vv.z = of[mi][ni][2] * inv;
      vv.w = of[mi][ni][3] * inv;
      *(float4*)(obase + ni * 16) = vv;
    }
  }
}

extern "C" void kernel_launch(void* const* d_in, const int* in_sizes, int n_in,
                              void* d_out, int out_size, void* d_ws, size_t ws_size,
                              hipStream_t stream) {
  const float* hs = (const float*)d_in[0];
  const float* Wq = (const float*)d_in[1];
  const float* bq = (const float*)d_in[2];
  const float* Wk = (const float*)d_in[3];
  const float* bk = (const float*)d_in[4];
  const float* Wv = (const float*)d_in[5];
  const float* bv = (const float*)d_in[6];
  float* out = (float*)d_out;

  // ws (bf16): Xb[8M] | Wt[3M] | QKV[24M]; V slot holds Vt[bh][d][s].
  ushort_t* Xb  = (ushort_t*)d_ws;
  ushort_t* Wt  = Xb + 8388608u;
  ushort_t* QKV = Wt + 3145728u;
  ushort_t* Vtp = QKV + 16777216u;

  conv_xw<<<8960, 256, 0, stream>>>((const float4*)hs, Xb, Wq, Wk, Wv, Wt);
  qkv_gemm<<<dim3(24, 64), 256, 0, stream>>>(Xb, Wt, bq, bk, bv, QKV);
  attn<<<dim3(8, 64), 512, 0, stream>>>(QKV, Vtp, out);
}

// Round 16
// 229.118 us; speedup vs baseline: 1.0460x; 1.0075x over previous
//
#include <hip/hip_runtime.h>
#include <hip/hip_bf16.h>
#include <stdint.h>

#define B_ 4
#define S_ 2048
#define H_ 1024
#define NH_ 16
#define HD_ 64
#define SCALE_ 0.125f
#define LOG2E_ 1.4426950408889634f

typedef __bf16 bf16x8 __attribute__((ext_vector_type(8)));
typedef float f32x4 __attribute__((ext_vector_type(4)));
typedef unsigned short us4 __attribute__((ext_vector_type(4)));
typedef unsigned short us8 __attribute__((ext_vector_type(8)));
typedef unsigned short ushort_t;

__device__ __forceinline__ ushort_t f2bf(float f) {
  union { float f; uint32_t u; } a; a.f = f;
  uint32_t r = (a.u + 0x7fffu + ((a.u >> 16) & 1u)) >> 16;
  return (ushort_t)r;
}

__device__ __forceinline__ void async16(const void* g, void* l) {
  __builtin_amdgcn_global_load_lds(
      (const __attribute__((address_space(1))) unsigned int*)(uintptr_t)g,
      (__attribute__((address_space(3))) unsigned int*)(uintptr_t)l, 16, 0, 0);
}

// raw workgroup barrier: no implicit vmcnt/lgkmcnt drain (unlike
// __syncthreads, which drains the global_load_lds queue - m97's ~20% stall).
// "memory" clobber stops the compiler moving LDS/VMEM ops across it.
__device__ __forceinline__ void raw_barrier() {
  asm volatile("s_barrier" ::: "memory");
}

// ------- merged conversion kernel: one launch instead of two ---------
// blocks 0..8191: hidden_states fp32 -> bf16 (conv_x path)
// blocks 8192..8959: W conv+transpose W[k][n] -> Wt[w][n][k] (conv_w)
// Branch is block-uniform -> the barrier in the W path is safe.
__global__ __launch_bounds__(256) void conv_xw(const float4* __restrict__ x,
                                               ushort_t* __restrict__ xb,
                                               const float* __restrict__ Wq,
                                               const float* __restrict__ Wk,
                                               const float* __restrict__ Wv,
                                               ushort_t* __restrict__ Wt) {
  __shared__ __align__(16) ushort_t T[64 * 64];
  int bid = blockIdx.x;
  int tid = threadIdx.x;
  if (bid < 8192) {
    int i = bid * 256 + tid;
    float4 v = x[i];
    us4 o;
    o.x = f2bf(v.x); o.y = f2bf(v.y); o.z = f2bf(v.z); o.w = f2bf(v.w);
    *(us4*)(xb + (size_t)i * 4) = o;
    return;
  }
  int wid = bid - 8192;            // 0..767
  int w = wid >> 8;
  int t2 = wid & 255;
  int kt = (t2 >> 4) * 64, nt = (t2 & 15) * 64;
  const float* W = (w == 0) ? Wq : (w == 1) ? Wk : Wv;
  int k = tid >> 2, nq = tid & 3;
#pragma unroll
  for (int j4 = 0; j4 < 4; ++j4) {
    int n = nq * 4 + j4 * 16;
    float4 f = *(const float4*)(W + (size_t)(kt + k) * H_ + nt + n);
    us4 o;
    o.x = f2bf(f.x); o.y = f2bf(f.y); o.z = f2bf(f.z); o.w = f2bf(f.w);
    *(us4*)(T + k * 64 + (((n >> 3) ^ (k & 7)) * 8) + (n & 7)) = o;
  }
  __syncthreads();
  int n2 = tid >> 2, kq = tid & 3;
  us8 o0, o1;
#pragma unroll
  for (int j = 0; j < 16; ++j) {
    int kk = kq * 16 + j;
    ushort_t v = T[kk * 64 + (((n2 >> 3) ^ (kk & 7)) * 8) + (n2 & 7)];
    if (j < 8) o0[j] = v; else o1[j - 8] = v;
  }
  size_t obase = (size_t)w * (H_ * H_) + (size_t)(nt + n2) * H_ + kt + kq * 16;
  *(us8*)(Wt + obase) = o0;
  *(us8*)(Wt + obase + 8) = o1;
}

// ---------------- fused QKV GEMM (BK=64 + T3 single-barrier dbuf) ----
// Measured-best form (round-13): BK=64, XOR-8 swizzle, raw-barrier
// dbuf, default block mapping (both XCD swizzles regressed - R3/R14).
// w==2 (V) epilogue writes transposed [bh][d][s] into the V slot so attn
// can stage V^T directly.
__global__ __launch_bounds__(256) void qkv_gemm(const ushort_t* __restrict__ Xb,
                                                const ushort_t* __restrict__ Wt,
                                                const float* __restrict__ bq,
                                                const float* __restrict__ bk,
                                                const float* __restrict__ bv,
                                                ushort_t* __restrict__ QKV) {
  __shared__ __align__(16) ushort_t As0[128 * 64];   // 16 KB
  __shared__ __align__(16) ushort_t As1[128 * 64];   // 16 KB
  __shared__ __align__(16) ushort_t Bs0[128 * 64];   // 16 KB
  __shared__ __align__(16) ushort_t Bs1[128 * 64];   // 16 KB
  int nb = blockIdx.x;             // 0..23
  int mb = blockIdx.y;             // 0..63
  int w = nb >> 3;
  int n_base = (nb & 7) * 128;
  int m_base = mb * 128;
  const ushort_t* Wtw = Wt + (size_t)w * (H_ * H_);
  int tid = threadIdx.x;
  int lane = tid & 63, wave = tid >> 6;
  int wr = wave >> 1, wc = wave & 1;
  int g = lane >> 4, l15 = lane & 15;

  f32x4 acc[4][4];
#pragma unroll
  for (int i = 0; i < 4; i++)
#pragma unroll
    for (int j = 0; j < 4; j++) acc[i][j] = (f32x4){0.f, 0.f, 0.f, 0.f};

  // staging: 8 chunks/thread/iter (4 for A, 4 for B). chunk id = tid+it*256
  // -> (row = id>>3, slot = id&7); rows step by 32 per it (low 3 bits of
  // row invariant -> one source-column xor per thread).
  int r0 = tid >> 3, sl = tid & 7;
  int cc = sl ^ (r0 & 7);
  const ushort_t* sA = Xb + (size_t)(m_base + r0) * H_ + cc * 8;
  const ushort_t* sB = Wtw + (size_t)(n_base + r0) * H_ + cc * 8;
  int la = tid * 8;                // ushort offset of chunk id (it adds 2048)

  // prologue: stage tile 0, publish
#pragma unroll
  for (int it = 0; it < 4; ++it) {
    async16(sA + (size_t)it * 32 * H_, As0 + la + it * 2048);
    async16(sB + (size_t)it * 32 * H_, Bs0 + la + it * 2048);
  }
  __builtin_amdgcn_s_waitcnt(0xF70);   // vmcnt(0)
  raw_barrier();

  for (int kt = 0; kt < 16; ++kt) {
    const ushort_t* Ac = (kt & 1) ? As1 : As0;
    const ushort_t* Bc = (kt & 1) ? Bs1 : Bs0;
    ushort_t* An = (kt & 1) ? As0 : As1;
    ushort_t* Bn = (kt & 1) ? Bs0 : Bs1;
    if (kt < 15) {
      int k0 = (kt + 1) * 64;
#pragma unroll
      for (int it = 0; it < 4; ++it) {
        async16(sA + (size_t)it * 32 * H_ + k0, An + la + it * 2048);
        async16(sB + (size_t)it * 32 * H_ + k0, Bn + la + it * 2048);
      }
    }

#pragma unroll
    for (int ks = 0; ks < 2; ++ks) {
      bf16x8 af[4], bfr[4];
#pragma unroll
      for (int mi = 0; mi < 4; mi++) {
        int row = wr * 64 + mi * 16 + l15;
        af[mi] = *(const bf16x8*)(Ac + row * 64 + (((ks * 4 + g) ^ (row & 7)) * 8));
      }
#pragma unroll
      for (int ni = 0; ni < 4; ni++) {
        int row = wc * 64 + ni * 16 + l15;
        bfr[ni] = *(const bf16x8*)(Bc + row * 64 + (((ks * 4 + g) ^ (row & 7)) * 8));
      }
#pragma unroll
      for (int mi = 0; mi < 4; mi++)
#pragma unroll
        for (int ni = 0; ni < 4; ni++)
          acc[mi][ni] = __builtin_amdgcn_mfma_f32_16x16x32_bf16(af[mi], bfr[ni], acc[mi][ni], 0, 0, 0);
    }

    if (kt < 15) {
      __builtin_amdgcn_s_waitcnt(0xF70);   // vmcnt(0): tile kt+1 landed
      raw_barrier();                       // publish; no re-drain
    }
  }

  const float* bias = (w == 0) ? bq : (w == 1) ? bk : bv;
  float mult = (w == 0) ? SCALE_ * LOG2E_ : 1.0f;  // fold scale*log2e into Q
  if (w == 2) {
    // V: write transposed Vt[bh][d][s], 8B stores (4 consecutive s per lane)
    ushort_t* Vout = QKV + 16777216u;
#pragma unroll
    for (int ni = 0; ni < 4; ++ni) {
      int n_col = n_base + wc * 64 + ni * 16 + l15;
      float bb = bias[n_col];
      int hh = n_col >> 6, d = n_col & 63;
#pragma unroll
      for (int mi = 0; mi < 4; ++mi) {
        int m_row = m_base + wr * 64 + mi * 16 + g * 4;
        int bbi = m_row >> 11, s = m_row & 2047;
        us4 o;
#pragma unroll
        for (int reg = 0; reg < 4; ++reg) o[reg] = f2bf(acc[mi][ni][reg] + bb);
        *(us4*)(Vout + ((size_t)((bbi * 16 + hh) * 64 + d)) * 2048 + s) = o;
      }
    }
  } else {
    ushort_t* out = QKV + (size_t)w * (8192u * 1024u);
#pragma unroll
    for (int ni = 0; ni < 4; ++ni) {
      int n_col = n_base + wc * 64 + ni * 16 + l15;
      float bb = bias[n_col];
#pragma unroll
      for (int mi = 0; mi < 4; ++mi) {
        int m_row = m_base + wr * 64 + mi * 16 + g * 4;
#pragma unroll
        for (int reg = 0; reg < 4; ++reg) {
          float v = (acc[mi][ni][reg] + bb) * mult;
          out[(size_t)(m_row + reg) * H_ + n_col] = f2bf(v);
        }
      }
    }
  }
}

// ---------------- flash attention, zero-P-LDS form -------------------
// Round-16: phase-interleaved iteration body. R15 proved the mi-level
// S-burst neutral (compiler already did it); the remaining serializer
// is the post-barrier convoy: all 16 waves/CU do {16 LDS reads} then
// {MFMAs} in lockstep, so the LDS phase (~27us/CU) and matrix phase
// (~37us/CU) barely overlap (69.8 ~ sum, not max). This round
// explicitly interleaves: read K(kk0) -> S-burst(kk0) || read K(kk1)
// -> S-burst(kk1) || {read V(kk), softmax, PV}(kk=0,1) - every LDS
// group after the first runs under the matrix pipe's prior burst.
// Accumulator chain order unchanged -> bit-identical output. VGPR
// ~115-125 (must stay <=128 for 4 waves/SIMD - check counter).
__global__ __launch_bounds__(512, 4) void attn(const ushort_t* __restrict__ QKV,
                                               const ushort_t* __restrict__ Vt,
                                               float* __restrict__ out) {
  __shared__ __align__(16) ushort_t Ks[3][64 * 64];   // 24 KB
  __shared__ __align__(16) ushort_t Vs[3][64 * 64];   // 24 KB
  int qt = blockIdx.x;   // 0..7
  int bh = blockIdx.y;   // 0..63
  int b = bh >> 4, h = bh & 15;
  int tid = threadIdx.x, lane = tid & 63, wave = tid >> 6;  // wave 0..7
  int g = lane >> 4, l15 = lane & 15;

  const ushort_t* Qb = QKV;
  const ushort_t* Kb = QKV + 8388608u;

  // Q B-frags: 32 q rows per wave (scale*log2e pre-folded into Q)
  bf16x8 qf[2][2];
#pragma unroll
  for (int mi = 0; mi < 2; ++mi) {
    int q_row = qt * 256 + wave * 32 + mi * 16 + l15;
    size_t qoff = (size_t)(b * S_ + q_row) * H_ + h * HD_;
    qf[mi][0] = *(const bf16x8*)(Qb + qoff + g * 8);
    qf[mi][1] = *(const bf16x8*)(Qb + qoff + 32 + g * 8);
  }

  // all-ones A-fragment for the row-sum MFMA (bit pattern 0x3F80 = bf16 1.0)
  union { us8 u; bf16x8 v; } ones_u;
#pragma unroll
  for (int i = 0; i < 8; ++i) ones_u.u[i] = 0x3F80;
  bf16x8 onesf = ones_u.v;

  f32x4 of[2][4];
  f32x4 lacc[2];
#pragma unroll
  for (int mi = 0; mi < 2; mi++) {
    lacc[mi] = (f32x4){0.f, 0.f, 0.f, 0.f};
#pragma unroll
    for (int ni = 0; ni < 4; ni++) of[mi][ni] = (f32x4){0.f, 0.f, 0.f, 0.f};
  }

  // interleaved A-row for S^T: row_a = kk*32 + (l15>>2)*8 + (l15&3), row_b = +4
  int ra = (l15 >> 2) * 8 + (l15 & 3);
  int sKa = ((l15 >> 2) & 1) * 4 + (l15 & 3);   // sigma_K of both rows
  int posK0 = (g ^ sKa) * 8, posK1 = ((4 + g) ^ sKa) * 8;

  // staging: 512 threads x 1 chunk per 8KB tile (K and V each)
  int ch = tid;                    // 0..511
  int s0 = ch >> 3;
  int cK = (ch & 7) ^ ((((s0 >> 3) & 1) << 2) | (s0 & 3));
  int cV = (ch & 7) ^ (s0 & 7);
  const ushort_t* srcK = Kb + (size_t)(b * S_ + s0) * H_ + h * HD_ + cK * 8;
  const ushort_t* srcV = Vt + ((size_t)bh * 64 + s0) * S_ + cV * 8;

  // preload tile 0 into buffer 0
  async16(srcK, Ks[0] + ch * 8);
  async16(srcV, Vs[0] + ch * 8);

  // rotation: Kc/Vc = current tile t; Kw/Vw = write target (holds t-2);
  // Kp/Vp = previous (t-1, may still be under read by laggard waves).
  const ushort_t* Kc = Ks[0];
  const ushort_t* Vc = Vs[0];
  ushort_t* Kw = (ushort_t*)Ks[1];
  ushort_t* Vw = (ushort_t*)Vs[1];
  const ushort_t* Kp = Ks[2];
  const ushort_t* Vp = Vs[2];

  for (int kb = 0; kb < 32; ++kb) {
    if (kb < 31) {
      async16(srcK + (size_t)(kb + 1) * 64 * H_, Kw + ch * 8);
      async16(srcV + (size_t)(kb + 1) * 64, Vw + ch * 8);
      __builtin_amdgcn_s_waitcnt(0xF72);   // vmcnt(2): own tile-kb loads landed
    } else {
      __builtin_amdgcn_s_waitcnt(0xF70);   // vmcnt(0)
    }
    raw_barrier();                          // publish tile kb (single barrier)

    // ---- phase-interleaved body: S(kk0) || read K(kk1), then S(kk1)
    // overlaps softmax(kk0); PV(kk) overlaps V-read(kk+1). S[kk][mi*2+v]
    // indexed compile-time only (rule #20 safe).
    f32x4 S[2][4];
#pragma unroll
    for (int kk = 0; kk < 2; ++kk) {
      int rowa = kk * 32 + ra;
      int rowb = rowa + 4;
      bf16x8 ka0 = *(const bf16x8*)(Kc + rowa * 64 + posK0);
      bf16x8 ka1 = *(const bf16x8*)(Kc + rowa * 64 + posK1);
      bf16x8 kb0 = *(const bf16x8*)(Kc + rowb * 64 + posK0);
      bf16x8 kb1 = *(const bf16x8*)(Kc + rowb * 64 + posK1);
      S[kk][0] = (f32x4){0.f, 0.f, 0.f, 0.f};
      S[kk][1] = (f32x4){0.f, 0.f, 0.f, 0.f};
      S[kk][2] = (f32x4){0.f, 0.f, 0.f, 0.f};
      S[kk][3] = (f32x4){0.f, 0.f, 0.f, 0.f};
      S[kk][0] = __builtin_amdgcn_mfma_f32_16x16x32_bf16(ka0, qf[0][0], S[kk][0], 0, 0, 0);
      S[kk][0] = __builtin_amdgcn_mfma_f32_16x16x32_bf16(ka1, qf[0][1], S[kk][0], 0, 0, 0);
      S[kk][1] = __builtin_amdgcn_mfma_f32_16x16x32_bf16(kb0, qf[0][0], S[kk][1], 0, 0, 0);
      S[kk][1] = __builtin_amdgcn_mfma_f32_16x16x32_bf16(kb1, qf[0][1], S[kk][1], 0, 0, 0);
      S[kk][2] = __builtin_amdgcn_mfma_f32_16x16x32_bf16(ka0, qf[1][0], S[kk][2], 0, 0, 0);
      S[kk][2] = __builtin_amdgcn_mfma_f32_16x16x32_bf16(ka1, qf[1][1], S[kk][2], 0, 0, 0);
      S[kk][3] = __builtin_amdgcn_mfma_f32_16x16x32_bf16(kb0, qf[1][0], S[kk][3], 0, 0, 0);
      S[kk][3] = __builtin_amdgcn_mfma_f32_16x16x32_bf16(kb1, qf[1][1], S[kk][3], 0, 0, 0);
    }

#pragma unroll
    for (int kk = 0; kk < 2; ++kk) {
      bf16x8 vf[4];
#pragma unroll
      for (int ni = 0; ni < 4; ++ni) {
        int row = ni * 16 + l15;
        vf[ni] = *(const bf16x8*)(Vc + row * 64 + (((kk * 4 + g) ^ (row & 7)) * 8));
      }
#pragma unroll
      for (int mi = 0; mi < 2; ++mi) {
        f32x4 sa = S[kk][mi * 2 + 0];
        f32x4 sb = S[kk][mi * 2 + 1];
        float pa0 = __builtin_amdgcn_exp2f(sa[0]);
        float pa1 = __builtin_amdgcn_exp2f(sa[1]);
        float pa2 = __builtin_amdgcn_exp2f(sa[2]);
        float pa3 = __builtin_amdgcn_exp2f(sa[3]);
        float pb0 = __builtin_amdgcn_exp2f(sb[0]);
        float pb1 = __builtin_amdgcn_exp2f(sb[1]);
        float pb2 = __builtin_amdgcn_exp2f(sb[2]);
        float pb3 = __builtin_amdgcn_exp2f(sb[3]);
        union { bf16x8 v; unsigned int u[4]; } pf;
        // truncation pack: high-16 extraction only (no +0x8000 RNE adds).
        // Denominator (lacc) uses the same truncated pf -> bias cancels.
        pf.u[0] = __builtin_amdgcn_perm(__float_as_uint(pa1),
                                        __float_as_uint(pa0), 0x07060302u);
        pf.u[1] = __builtin_amdgcn_perm(__float_as_uint(pa3),
                                        __float_as_uint(pa2), 0x07060302u);
        pf.u[2] = __builtin_amdgcn_perm(__float_as_uint(pb1),
                                        __float_as_uint(pb0), 0x07060302u);
        pf.u[3] = __builtin_amdgcn_perm(__float_as_uint(pb3),
                                        __float_as_uint(pb2), 0x07060302u);
#pragma unroll
        for (int ni = 0; ni < 4; ++ni)
          of[mi][ni] = __builtin_amdgcn_mfma_f32_16x16x32_bf16(vf[ni], pf.v, of[mi][ni], 0, 0, 0);
        // row-sum on the matrix pipe: lacc[mi][*] = sum_k P[k][q=l15]
        lacc[mi] = __builtin_amdgcn_mfma_f32_16x16x32_bf16(onesf, pf.v, lacc[mi], 0, 0, 0);
      }
    }

    // rotate buffers: (Kp, Kc, Kw) <- (Kc, Kw, Kp)
    const ushort_t* tK = Kp; Kp = Kc; Kc = Kw; Kw = (ushort_t*)tK;
    const ushort_t* tV = Vp; Vp = Vc; Vc = Vw; Vw = (ushort_t*)tV;
  }

  // ---- epilogue: O^T / l, float4 stores (no shfl: lacc holds full sum) ----
#pragma unroll
  for (int mi = 0; mi < 2; ++mi) {
    float inv = 1.0f / lacc[mi][0];
    int qglob = qt * 256 + wave * 32 + mi * 16 + l15;
    float* obase = out + (size_t)(b * S_ + qglob) * H_ + h * HD_ + g * 4;
#pragma unroll
    for (int ni = 0; ni < 4; ++ni) {
      float4 vv;
      vv.x = of[mi][ni][0] * inv;
      vv.y = of[mi][ni][1] * inv;
      vv.z = of[mi][ni][2] * inv;
      vv.w = of[mi][ni][3] * inv;
      *(float4*)(obase + ni * 16) = vv;
    }
  }
}

extern "C" void kernel_launch(void* const* d_in, const int* in_sizes, int n_in,
                              void* d_out, int out_size, void* d_ws, size_t ws_size,
                              hipStream_t stream) {
  const float* hs = (const float*)d_in[0];
  const float* Wq = (const float*)d_in[1];
  const float* bq = (const float*)d_in[2];
  const float* Wk = (const float*)d_in[3];
  const float* bk = (const float*)d_in[4];
  const float* Wv = (const float*)d_in[5];
  const float* bv = (const float*)d_in[6];
  float* out = (float*)d_out;

  // ws (bf16): Xb[8M] | Wt[3M] | QKV[24M]; V slot holds Vt[bh][d][s].
  ushort_t* Xb  = (ushort_t*)d_ws;
  ushort_t* Wt  = Xb + 8388608u;
  ushort_t* QKV = Wt + 3145728u;
  ushort_t* Vtp = QKV + 16777216u;

  conv_xw<<<8960, 256, 0, stream>>>((const float4*)hs, Xb, Wq, Wk, Wv, Wt);
  qkv_gemm<<<dim3(24, 64), 256, 0, stream>>>(Xb, Wt, bq, bk, bv, QKV);
  attn<<<dim3(8, 64), 512, 0, stream>>>(QKV, Vtp, out);
}